// Round 15
// baseline (33.134 us; speedup 1.0000x reference)
//
#include <hip/hip_runtime.h>
#include <math.h>

#define NV 65536
#define NE 4096
#define NP 4096
#define NT 512
#define SENTF 1000000000.0f
#define BIGF 1e30f

// ---------------- wave(64) reduction helpers ----------------
__device__ __forceinline__ float waveMinF(float v) {
    #pragma unroll
    for (int o = 32; o; o >>= 1) v = fminf(v, __shfl_xor(v, o, 64));
    return v;
}
__device__ __forceinline__ float waveMaxF(float v) {
    #pragma unroll
    for (int o = 32; o; o >>= 1) v = fmaxf(v, __shfl_xor(v, o, 64));
    return v;
}
__device__ __forceinline__ int waveSumI(int v) {
    #pragma unroll
    for (int o = 32; o; o >>= 1) v += __shfl_xor(v, o, 64);
    return v;
}
__device__ __forceinline__ int waveMinI(int v) {
    #pragma unroll
    for (int o = 32; o; o >>= 1) v = min(v, __shfl_xor(v, o, 64));
    return v;
}

// ---------------- kernel 1: per-edge params + table repack (R7/R8-validated) ----------------
__global__ void prep_kernel(const float* __restrict__ verts,
                            const int*   __restrict__ edges,
                            const float* __restrict__ tab,
                            float*  __restrict__ ea,  float*  __restrict__ eb,
                            float2* __restrict__ pk2, float4* __restrict__ pk4,
                            float4* __restrict__ tb4) {
    int e = blockIdx.x * blockDim.x + threadIdx.x;
    if (e < NT) {
        const float* r = tab + 7 * e;
        tb4[e] = make_float4(r[3], r[4], r[5], r[6]);
    }
    if (e >= NE) return;
    int i0 = edges[2 * e + 0];
    int i1 = edges[2 * e + 1];
    float x0 = verts[3 * i0 + 0], y0 = verts[3 * i0 + 1];
    float x1 = verts[3 * i1 + 0], y1 = verts[3 * i1 + 1];
    float a = (y0 - y1) / (x0 - x1);
    float b = y0 - a * x0;
    ea[e] = a; eb[e] = b;
    pk2[e] = make_float2(fminf(x0, x1), fmaxf(x0, x1));
    pk4[e] = make_float4(fminf(y0, y1), fmaxf(y0, y1), 1.0f / a, b);  // reciprocal hoisted
}

// ---------------- kernel 2: 4 points/block, 8 waves, edge-EIGHTH per wave ----------------
// 1024 blocks x 512 thr = 8 waves -> 8192 waves = 8 waves/SIMD (2x champion TLP).
// Wave w covers edges [w*512,(w+1)*512) for ALL 4 points (x4 load reuse kept).
__global__ __launch_bounds__(512, 8) void point_kernel(
        const float*  __restrict__ verts,
        const int*    __restrict__ listAll,
        const float*  __restrict__ ea,  const float*  __restrict__ eb,
        const float2* __restrict__ pk2, const float4* __restrict__ pk4,
        const float4* __restrict__ tb4,
        float* __restrict__ mOut, int* __restrict__ vOut) {
    __shared__ float sCY[4], sPX[4], sL1[4], sL2v[4];
    __shared__ float sQ[8][4][6];   // [wave][point][stat]
    __shared__ float sF[4][6];      // folded per point
    __shared__ float sPM[8];
    __shared__ int   sVal[4];

    const int tid  = threadIdx.x;
    const int lane = tid & 63;
    const int w    = tid >> 6;       // 0..7
    const int pBase = blockIdx.x * 4;

    // ---- phase 1: waves 0..3, one point each (R8-validated early-exit) ----
    if (w < 4) {
        int p  = pBase + w;
        int vi = listAll[p];
        float px = verts[3 * vi + 0];
        float py = verts[3 * vi + 1];
        int minIdx = NE;
        for (int it = 0; it < NE / 64; ++it) {
            int e = it * 64 + lane;
            float2 q = pk2[e];
            bool hit = (px > q.x) && (px < q.y);
            if (hit) minIdx = e;
            if (__any(hit)) break;
        }
        minIdx = waveMinI(minIdx);
        int idx = (minIdx >= NE) ? (NE - 1) : minIdx;
        float exposeY = ea[idx] * px + eb[idx];
        if (lane == 0) {
            sCY[w] = 0.5f * (py + exposeY);
            sL1[w] = fabsf(py - exposeY);
            sPX[w] = px;
        }
    }
    __syncthreads();

    float cyv[4], cxv[4];
    #pragma unroll
    for (int p = 0; p < 4; ++p) { cyv[p] = sCY[p]; cxv[p] = sPX[p]; }

    // ---- phase 2: per-point accumulators, wave w covers its eighth (R8 body) ----
    float mx[4], mn[4], xs[4], xf[4];
    int   nC[4], hh[4];               // hh = hasS | hasI<<16
    #pragma unroll
    for (int p = 0; p < 4; ++p) {
        mx[p] = -SENTF; mn[p] = SENTF; xs[p] = SENTF; xf[p] = -SENTF;
        nC[p] = 0; hh[p] = 0;
    }

    #pragma unroll 4
    for (int it = 0; it < 8; ++it) {
        float4 q = pk4[w * 512 + it * 64 + lane];    // (ymn, ymx, 1/a, b)
        #pragma unroll
        for (int p = 0; p < 4; ++p) {
            float cy = cyv[p], cx = cxv[p];
            bool  c  = (cy > q.x) && (cy < q.y);
            float xi = (cy - q.w) * q.z;             // identical arithmetic to validated path
            nC[p] += c ? 1 : 0;
            mx[p] = fmaxf(mx[p], c ? xi : -SENTF);
            mn[p] = fminf(mn[p], c ? xi :  SENTF);
            bool sp  = c && (xi >= cx);
            bool in_ = c && (xi <  cx);
            xs[p] = fminf(xs[p], sp  ? xi :  SENTF);
            xf[p] = fmaxf(xf[p], in_ ? xi : -SENTF);
            hh[p] |= (sp ? 1 : 0) | (in_ ? 0x10000 : 0);
        }
    }

    // ---- wave-reduce each point's stats, lane0 -> LDS (validated) ----
    #pragma unroll
    for (int p = 0; p < 4; ++p) {
        float a0 = waveMaxF(mx[p]);
        float a1 = waveMinF(mn[p]);
        float a2 = waveMinF(xs[p]);
        float a3 = waveMaxF(xf[p]);
        int   a4 = waveSumI(nC[p]);
        int   a5 = waveSumI(hh[p]);   // fields <= 64 each per wave
        if (lane == 0) {
            sQ[w][p][0] = a0; sQ[w][p][1] = a1;
            sQ[w][p][2] = a2; sQ[w][p][3] = a3;
            sQ[w][p][4] = __int_as_float(a4);
            sQ[w][p][5] = __int_as_float(a5);
        }
    }
    __syncthreads();

    // ---- fold 8 waves: 24 threads, one (point, stat) each (exact ops) ----
    if (tid < 24) {
        int p = tid & 3, s = tid >> 2;   // s in 0..5
        if (s == 0) {
            float a0 = sQ[0][p][0];
            #pragma unroll
            for (int ww = 1; ww < 8; ++ww) a0 = fmaxf(a0, sQ[ww][p][0]);
            sF[p][0] = a0;
        } else if (s == 1) {
            float a0 = sQ[0][p][1];
            #pragma unroll
            for (int ww = 1; ww < 8; ++ww) a0 = fminf(a0, sQ[ww][p][1]);
            sF[p][1] = a0;
        } else if (s == 2) {
            float a0 = sQ[0][p][2];
            #pragma unroll
            for (int ww = 1; ww < 8; ++ww) a0 = fminf(a0, sQ[ww][p][2]);
            sF[p][2] = a0;
        } else if (s == 3) {
            float a0 = sQ[0][p][3];
            #pragma unroll
            for (int ww = 1; ww < 8; ++ww) a0 = fmaxf(a0, sQ[ww][p][3]);
            sF[p][3] = a0;
        } else if (s == 4) {
            int a0 = 0;
            #pragma unroll
            for (int ww = 0; ww < 8; ++ww) a0 += __float_as_int(sQ[ww][p][4]);
            sF[p][4] = __int_as_float(a0);
        } else {
            int a0 = 0;
            #pragma unroll
            for (int ww = 0; ww < 8; ++ww) a0 += __float_as_int(sQ[ww][p][5]);
            sF[p][5] = __int_as_float(a0);
        }
    }
    __syncthreads();

    // ---- per-point finish: valid, L2 (validated) ----
    if (tid < 4) {
        int n  = __float_as_int(sF[tid][4]);
        int hc = __float_as_int(sF[tid][5]);
        int hS = hc & 0xFFFF, hI = hc >> 16;
        bool valid = (n == 2) || ((n > 2) && (hS > 0) && (hI > 0));
        float dx = (n == 2) ? (sF[tid][0] - sF[tid][1]) : (sF[tid][2] - sF[tid][3]);
        sL2v[tid] = fabsf(dx);
        sVal[tid] = valid ? 1 : 0;
    }
    __syncthreads();

    // ---- table min: wave w -> point w&3, table half w>>2 (min is exact) ----
    {
        int pt = w & 3, hf = w >> 2;
        float L1v = sL1[pt], L2 = sL2v[pt];
        float d1  = fabsf(sCY[pt] - 1.0f);
        float d2  = fabsf(sPX[pt] - 1.0f);
        float pm = INFINITY;
        #pragma unroll
        for (int kk = 0; kk < NT / 128; ++kk) {
            float4 r = tb4[hf * (NT / 2) + kk * 64 + lane];
            float al = fabsf(L1v - r.x) + fabsf(L2 - r.y) +
                       fabsf(d1 - r.z) + fabsf(d2 - r.w);
            pm = fminf(pm, al);
        }
        pm = waveMinF(pm);
        if (lane == 0) sPM[w] = pm;
    }
    __syncthreads();

    if (tid < 4) {
        float pm = fminf(sPM[tid], sPM[tid + 4]);
        mOut[pBase + tid] = sVal[tid] ? pm : BIGF;
        vOut[pBase + tid] = sVal[tid];
    }
}

// ---------------- kernel 3: cummin + masked sum (validated) ----------------
__global__ __launch_bounds__(1024) void scan_kernel(const float* __restrict__ m,
                                                    const int*   __restrict__ valid,
                                                    float* __restrict__ out) {
    __shared__ float wAgg[16];
    __shared__ float wSum[16];
    int t = threadIdx.x;
    int lane = t & 63, wid = t >> 6;

    float v[4]; int vl[4];
    #pragma unroll
    for (int j = 0; j < 4; j++) { v[j] = m[4 * t + j]; vl[j] = valid[4 * t + j]; }
    float cmin = fminf(fminf(v[0], v[1]), fminf(v[2], v[3]));

    float inc = cmin;
    #pragma unroll
    for (int o = 1; o < 64; o <<= 1) {
        float u = __shfl_up(inc, o, 64);
        if (lane >= o) inc = fminf(inc, u);
    }
    if (lane == 63) wAgg[wid] = inc;
    __syncthreads();

    float wavePrefix = INFINITY;
    for (int i = 0; i < wid; i++) wavePrefix = fminf(wavePrefix, wAgg[i]);
    float excl = __shfl_up(inc, 1, 64);
    if (lane == 0) excl = INFINITY;
    float run = fminf(wavePrefix, excl);

    float sum = 0.0f;
    #pragma unroll
    for (int j = 0; j < 4; j++) {
        run = fminf(run, v[j]);
        if (vl[j]) sum += run;
    }
    #pragma unroll
    for (int o = 32; o; o >>= 1) sum += __shfl_xor(sum, o, 64);
    if (lane == 0) wSum[wid] = sum;
    __syncthreads();
    if (t == 0) {
        float s = 0.0f;
        for (int i = 0; i < 16; i++) s += wSum[i];
        out[0] = s;
    }
}

extern "C" void kernel_launch(void* const* d_in, const int* in_sizes, int n_in,
                              void* d_out, int out_size, void* d_ws, size_t ws_size,
                              hipStream_t stream) {
    const float* verts   = (const float*)d_in[0];
    const float* tab     = (const float*)d_in[1];
    const int*   edges   = (const int*)d_in[2];
    const int*   listAll = (const int*)d_in[3];

    char* ws = (char*)d_ws;
    float4* pk4 = (float4*)ws;                    ws += NE * sizeof(float4);
    float4* tb4 = (float4*)ws;                    ws += NT * sizeof(float4);
    float2* pk2 = (float2*)ws;                    ws += NE * sizeof(float2);
    float*  ea  = (float*)ws;                     ws += NE * sizeof(float);
    float*  eb  = (float*)ws;                     ws += NE * sizeof(float);
    float*  mArr= (float*)ws;                     ws += NP * sizeof(float);
    int*    vArr= (int*)ws;

    prep_kernel<<<(NE + 255) / 256, 256, 0, stream>>>(verts, edges, tab,
                                                      ea, eb, pk2, pk4, tb4);
    point_kernel<<<NP / 4, 512, 0, stream>>>(verts, listAll,
                                             ea, eb, pk2, pk4, tb4,
                                             mArr, vArr);
    scan_kernel<<<1, 1024, 0, stream>>>(mArr, vArr, (float*)d_out);
}

// Round 16
// 27.695 us; speedup vs baseline: 1.1964x; 1.1964x over previous
//
#include <hip/hip_runtime.h>
#include <math.h>

#define NV 65536
#define NE 4096
#define NP 4096
#define NT 512
#define SENTF 1000000000.0f
#define BIGF 1e30f

// ---------------- wave(64) reduction helpers ----------------
__device__ __forceinline__ float waveMinF(float v) {
    #pragma unroll
    for (int o = 32; o; o >>= 1) v = fminf(v, __shfl_xor(v, o, 64));
    return v;
}
__device__ __forceinline__ float waveMaxF(float v) {
    #pragma unroll
    for (int o = 32; o; o >>= 1) v = fmaxf(v, __shfl_xor(v, o, 64));
    return v;
}
__device__ __forceinline__ int waveSumI(int v) {
    #pragma unroll
    for (int o = 32; o; o >>= 1) v += __shfl_xor(v, o, 64);
    return v;
}
__device__ __forceinline__ int waveMinI(int v) {
    #pragma unroll
    for (int o = 32; o; o >>= 1) v = min(v, __shfl_xor(v, o, 64));
    return v;
}

// ---------------- kernel 1: per-edge params + table repack (validated) ----------------
__global__ void prep_kernel(const float* __restrict__ verts,
                            const int*   __restrict__ edges,
                            const float* __restrict__ tab,
                            float*  __restrict__ ea,  float*  __restrict__ eb,
                            float2* __restrict__ pk2, float4* __restrict__ pk4,
                            float4* __restrict__ tb4) {
    int e = blockIdx.x * blockDim.x + threadIdx.x;
    if (e < NT) {
        const float* r = tab + 7 * e;
        tb4[e] = make_float4(r[3], r[4], r[5], r[6]);
    }
    if (e >= NE) return;
    int i0 = edges[2 * e + 0];
    int i1 = edges[2 * e + 1];
    float x0 = verts[3 * i0 + 0], y0 = verts[3 * i0 + 1];
    float x1 = verts[3 * i1 + 0], y1 = verts[3 * i1 + 1];
    float a = (y0 - y1) / (x0 - x1);
    float b = y0 - a * x0;
    ea[e] = a; eb[e] = b;
    pk2[e] = make_float2(fminf(x0, x1), fmaxf(x0, x1));
    pk4[e] = make_float4(fminf(y0, y1), fmaxf(y0, y1), 1.0f / a, b);  // reciprocal hoisted
}

// ---------------- kernel 2: 4 points/block, register-reuse phase 2 ----------------
// 1024 blocks x 256 thr = 4 waves. Wave w: phase-1 for point w; phase-2 covers
// edge quarter [w*1024,(w+1)*1024) for ALL 4 points (each pk4 load reused x4).
__global__ __launch_bounds__(256) void point_kernel(
        const float*  __restrict__ verts,
        const int*    __restrict__ listAll,
        const float*  __restrict__ ea,  const float*  __restrict__ eb,
        const float2* __restrict__ pk2, const float4* __restrict__ pk4,
        const float4* __restrict__ tb4,
        float* __restrict__ mOut, int* __restrict__ vOut) {
    __shared__ float sCY[4], sPX[4], sL1[4], sL2[4];
    __shared__ float sQ[4][4][6];   // [wave][point][stat]
    __shared__ float sF[4][6];      // folded per point
    __shared__ int   sVal[4];

    const int tid  = threadIdx.x;
    const int lane = tid & 63;
    const int w    = tid >> 6;       // 0..3
    const int pBase = blockIdx.x * 4;

    // ---- phase 1: wave w -> point pBase+w (validated early-exit search) ----
    {
        int p  = pBase + w;
        int vi = listAll[p];
        float px = verts[3 * vi + 0];
        float py = verts[3 * vi + 1];
        int minIdx = NE;
        for (int it = 0; it < NE / 64; ++it) {
            int e = it * 64 + lane;
            float2 q = pk2[e];
            bool hit = (px > q.x) && (px < q.y);
            if (hit) minIdx = e;
            if (__any(hit)) break;
        }
        minIdx = waveMinI(minIdx);
        int idx = (minIdx >= NE) ? (NE - 1) : minIdx;
        float exposeY = ea[idx] * px + eb[idx];
        if (lane == 0) {
            sCY[w] = 0.5f * (py + exposeY);
            sL1[w] = fabsf(py - exposeY);
            sPX[w] = px;
        }
    }
    __syncthreads();

    float cyv[4], cxv[4];
    #pragma unroll
    for (int p = 0; p < 4; ++p) { cyv[p] = sCY[p]; cxv[p] = sPX[p]; }

    // ---- phase 2: per-point accumulators, each edge load reused x4 ----
    float mx[4], mn[4], xs[4], xf[4];
    int   nC[4], hh[4];               // hh = hasS | hasI<<16
    #pragma unroll
    for (int p = 0; p < 4; ++p) {
        mx[p] = -SENTF; mn[p] = SENTF; xs[p] = SENTF; xf[p] = -SENTF;
        nC[p] = 0; hh[p] = 0;
    }

    #pragma unroll 4
    for (int it = 0; it < 16; ++it) {
        float4 q = pk4[w * 1024 + it * 64 + lane];   // (ymn, ymx, 1/a, b)
        #pragma unroll
        for (int p = 0; p < 4; ++p) {
            float cy = cyv[p], cx = cxv[p];
            bool  c  = (cy > q.x) && (cy < q.y);
            float xi = (cy - q.w) * q.z;             // identical arithmetic to validated path
            nC[p] += c ? 1 : 0;
            mx[p] = fmaxf(mx[p], c ? xi : -SENTF);
            mn[p] = fminf(mn[p], c ? xi :  SENTF);
            bool sp  = c && (xi >= cx);
            bool in_ = c && (xi <  cx);
            xs[p] = fminf(xs[p], sp  ? xi :  SENTF);
            xf[p] = fmaxf(xf[p], in_ ? xi : -SENTF);
            hh[p] |= (sp ? 1 : 0) | (in_ ? 0x10000 : 0);
        }
    }

    // ---- wave-reduce each point's stats, lane0 -> LDS ----
    #pragma unroll
    for (int p = 0; p < 4; ++p) {
        float a0 = waveMaxF(mx[p]);
        float a1 = waveMinF(mn[p]);
        float a2 = waveMinF(xs[p]);
        float a3 = waveMaxF(xf[p]);
        int   a4 = waveSumI(nC[p]);
        int   a5 = waveSumI(hh[p]);   // fields <= 64 each, no carry
        if (lane == 0) {
            sQ[w][p][0] = a0; sQ[w][p][1] = a1;
            sQ[w][p][2] = a2; sQ[w][p][3] = a3;
            sQ[w][p][4] = __int_as_float(a4);
            sQ[w][p][5] = __int_as_float(a5);
        }
    }
    __syncthreads();

    // ---- fold 4 waves: 24 threads, one (point, stat) each ----
    if (tid < 24) {
        int p = tid & 3, s = tid >> 2;   // s in 0..5
        if (s == 0)      sF[p][0] = fmaxf(fmaxf(sQ[0][p][0], sQ[1][p][0]), fmaxf(sQ[2][p][0], sQ[3][p][0]));
        else if (s == 1) sF[p][1] = fminf(fminf(sQ[0][p][1], sQ[1][p][1]), fminf(sQ[2][p][1], sQ[3][p][1]));
        else if (s == 2) sF[p][2] = fminf(fminf(sQ[0][p][2], sQ[1][p][2]), fminf(sQ[2][p][2], sQ[3][p][2]));
        else if (s == 3) sF[p][3] = fmaxf(fmaxf(sQ[0][p][3], sQ[1][p][3]), fmaxf(sQ[2][p][3], sQ[3][p][3]));
        else if (s == 4) sF[p][4] = __int_as_float(__float_as_int(sQ[0][p][4]) + __float_as_int(sQ[1][p][4])
                                                 + __float_as_int(sQ[2][p][4]) + __float_as_int(sQ[3][p][4]));
        else             sF[p][5] = __int_as_float(__float_as_int(sQ[0][p][5]) + __float_as_int(sQ[1][p][5])
                                                 + __float_as_int(sQ[2][p][5]) + __float_as_int(sQ[3][p][5]));
    }
    __syncthreads();

    // ---- per-point finish: valid, L2 ----
    if (tid < 4) {
        int n  = __float_as_int(sF[tid][4]);
        int hc = __float_as_int(sF[tid][5]);
        int hS = hc & 0xFFFF, hI = hc >> 16;
        bool valid = (n == 2) || ((n > 2) && (hS > 0) && (hI > 0));
        float dx = (n == 2) ? (sF[tid][0] - sF[tid][1]) : (sF[tid][2] - sF[tid][3]);
        sL2[tid]  = fabsf(dx);
        sVal[tid] = valid ? 1 : 0;
    }
    __syncthreads();

    // ---- table min: wave w -> point w (validated float4 path) ----
    {
        float L1v = sL1[w], L2v = sL2[w];
        float d1  = fabsf(sCY[w] - 1.0f);
        float d2  = fabsf(sPX[w] - 1.0f);
        float pm = INFINITY;
        #pragma unroll
        for (int kk = 0; kk < NT / 64; ++kk) {
            float4 r = tb4[kk * 64 + lane];
            float al = fabsf(L1v - r.x) + fabsf(L2v - r.y) +
                       fabsf(d1 - r.z) + fabsf(d2 - r.w);
            pm = fminf(pm, al);
        }
        pm = waveMinF(pm);
        if (lane == 0) {
            mOut[pBase + w] = sVal[w] ? pm : BIGF;
            vOut[pBase + w] = sVal[w];
        }
    }
}

// ---------------- kernel 3: cummin + masked sum (validated) ----------------
__global__ __launch_bounds__(1024) void scan_kernel(const float* __restrict__ m,
                                                    const int*   __restrict__ valid,
                                                    float* __restrict__ out) {
    __shared__ float wAgg[16];
    __shared__ float wSum[16];
    int t = threadIdx.x;
    int lane = t & 63, wid = t >> 6;

    float v[4]; int vl[4];
    #pragma unroll
    for (int j = 0; j < 4; j++) { v[j] = m[4 * t + j]; vl[j] = valid[4 * t + j]; }
    float cmin = fminf(fminf(v[0], v[1]), fminf(v[2], v[3]));

    float inc = cmin;
    #pragma unroll
    for (int o = 1; o < 64; o <<= 1) {
        float u = __shfl_up(inc, o, 64);
        if (lane >= o) inc = fminf(inc, u);
    }
    if (lane == 63) wAgg[wid] = inc;
    __syncthreads();

    float wavePrefix = INFINITY;
    for (int i = 0; i < wid; i++) wavePrefix = fminf(wavePrefix, wAgg[i]);
    float excl = __shfl_up(inc, 1, 64);
    if (lane == 0) excl = INFINITY;
    float run = fminf(wavePrefix, excl);

    float sum = 0.0f;
    #pragma unroll
    for (int j = 0; j < 4; j++) {
        run = fminf(run, v[j]);
        if (vl[j]) sum += run;
    }
    #pragma unroll
    for (int o = 32; o; o >>= 1) sum += __shfl_xor(sum, o, 64);
    if (lane == 0) wSum[wid] = sum;
    __syncthreads();
    if (t == 0) {
        float s = 0.0f;
        for (int i = 0; i < 16; i++) s += wSum[i];
        out[0] = s;
    }
}

extern "C" void kernel_launch(void* const* d_in, const int* in_sizes, int n_in,
                              void* d_out, int out_size, void* d_ws, size_t ws_size,
                              hipStream_t stream) {
    const float* verts   = (const float*)d_in[0];
    const float* tab     = (const float*)d_in[1];
    const int*   edges   = (const int*)d_in[2];
    const int*   listAll = (const int*)d_in[3];

    char* ws = (char*)d_ws;
    float4* pk4 = (float4*)ws;                    ws += NE * sizeof(float4);
    float4* tb4 = (float4*)ws;                    ws += NT * sizeof(float4);
    float2* pk2 = (float2*)ws;                    ws += NE * sizeof(float2);
    float*  ea  = (float*)ws;                     ws += NE * sizeof(float);
    float*  eb  = (float*)ws;                     ws += NE * sizeof(float);
    float*  mArr= (float*)ws;                     ws += NP * sizeof(float);
    int*    vArr= (int*)ws;

    prep_kernel<<<(NE + 255) / 256, 256, 0, stream>>>(verts, edges, tab,
                                                      ea, eb, pk2, pk4, tb4);
    point_kernel<<<NP / 4, 256, 0, stream>>>(verts, listAll,
                                             ea, eb, pk2, pk4, tb4,
                                             mArr, vArr);
    scan_kernel<<<1, 1024, 0, stream>>>(mArr, vArr, (float*)d_out);
}